// Round 5
// baseline (531.186 us; speedup 1.0000x reference)
//
#include <hip/hip_runtime.h>
#include <math.h>

// N=4, S=2048, D=1024, fp32 in/out.
// Pipeline:
//   wq = q@WQt, wk = k@WKt : f16-split MFMA GEMM, 3 products (hh+hl+lh), split-plane out
//   wvT = (v@WVt)^T        : 1-product (hh) GEMM, f16 hi-only transposed out
//   Sc = wq@wkt            : 3-product GEMM, f32 out, GLL-staged planes,
//                            column-stats PARTIALS fused into epilogue
//   stats combine          : fold 16 q-chunk partials -> m[k], r[k]=1/sum
//   out = (P @ wvT^T)/1024 : 1-product GEMM; A-staging computes P = exp(Sc-m)*r on the fly,
//                            B staged via GLL, natural block order for A-panel L2 reuse
// Workspace (10*NSD f16 units = 167.8 MB):
//   [0..4*NSD)   f16: wq_hi|wq_lo|wk_hi|wk_lo
//   [4*NSD..5*NSD) f16: wvT_hi  [N][D][S]
//   [5*NSD..9*NSD) f32: Sc (NSS floats)
//   [9*NSD..)    f32: pm|ps|statM|statR

typedef _Float16 f16;
typedef _Float16 f16x8 __attribute__((ext_vector_type(8)));
typedef float f32x4 __attribute__((ext_vector_type(4)));

enum StageMode { SM_F32SPLIT, SM_F32HI, SM_PLANES2, SM_PLANES1, SM_EXP };
enum EpiMode   { EPI_F32, EPI_SPLIT, EPI_F16T };

#define PAD_PITCH 40   // f16 units; 80 B = 5x16B chunks, coprime with 8 bank-quads
#define GLL_PITCH 32   // f16 units; unpadded, XOR-swizzled chunks

// async global->LDS, 16B per lane; LDS dest = wave-uniform base + lane*16
__device__ __forceinline__ void gll16(const f16* g, f16* l) {
    __builtin_amdgcn_global_load_lds(
        (const __attribute__((address_space(1))) void*)g,
        (__attribute__((address_space(3))) void*)l, 16, 0, 0);
}

// Stage one 128x32 f16 plane via GLL with XOR chunk swizzle.
// Physical slot t (16B) holds data (row = t>>2, chunk = (t&3) ^ ((row>>1)&3)).
__device__ __forceinline__ void stage_gll_plane(const f16* __restrict__ gplane,
                                                f16* __restrict__ lds,
                                                long rowBase, int ld, int k0,
                                                int wave, int lane)
{
#pragma unroll
    for (int i = 0; i < 2; i++) {
        int slotBase = (wave * 2 + i) * 64;
        int t = slotBase + lane;
        int r = t >> 2;
        int c = (t & 3) ^ ((r >> 1) & 3);
        const f16* g = gplane + (rowBase + r) * (long)ld + k0 + c * 8;
        gll16(g, lds + (long)slotBase * 8);   // wave-uniform LDS base
    }
}

// fragment LDS offset (f16 units) for the two layouts
__device__ __forceinline__ int frag_off_gll(int row, int g) {
    return row * GLL_PITCH + ((g ^ ((row >> 1) & 3)) << 3);
}
__device__ __forceinline__ int frag_off_pad(int row, int g) {
    return row * PAD_PITCH + (g << 3);
}

// Padded-layout staging for f32-source modes (VGPR round-trip + convert).
template<StageMode SM>
__device__ __forceinline__ void stage_f32_tile(const float* __restrict__ gf,
                                               const float* __restrict__ pM,
                                               const float* __restrict__ pR,
                                               f16* __restrict__ Shi, f16* __restrict__ Slo,
                                               long rowBase, int ld, int k0, int tid)
{
#pragma unroll
    for (int i = 0; i < 2; i++) {
        int c  = tid + i * 256;      // 512 chunks of 8 elements
        int r  = c >> 2;             // row 0..127
        int cc = c & 3;              // chunk within row
        long g = (rowBase + r) * (long)ld + k0 + cc * 8;
        float4 x0 = *(const float4*)&gf[g];
        float4 x1 = *(const float4*)&gf[g + 4];
        float xs[8] = {x0.x, x0.y, x0.z, x0.w, x1.x, x1.y, x1.z, x1.w};
        if constexpr (SM == SM_EXP) {
            float4 ma = *(const float4*)&pM[k0 + cc * 8];
            float4 mb = *(const float4*)&pM[k0 + cc * 8 + 4];
            float4 ra = *(const float4*)&pR[k0 + cc * 8];
            float4 rb = *(const float4*)&pR[k0 + cc * 8 + 4];
            float ms[8] = {ma.x, ma.y, ma.z, ma.w, mb.x, mb.y, mb.z, mb.w};
            float rs[8] = {ra.x, ra.y, ra.z, ra.w, rb.x, rb.y, rb.z, rb.w};
            f16x8 h;
#pragma unroll
            for (int e = 0; e < 8; e++)
                h[e] = (f16)(__expf(xs[e] - ms[e]) * rs[e]);
            *(f16x8*)&Shi[r * PAD_PITCH + cc * 8] = h;
        } else if constexpr (SM == SM_F32HI) {
            f16x8 h;
#pragma unroll
            for (int e = 0; e < 8; e++) h[e] = (f16)xs[e];
            *(f16x8*)&Shi[r * PAD_PITCH + cc * 8] = h;
        } else { // SM_F32SPLIT
            f16x8 h, l;
#pragma unroll
            for (int e = 0; e < 8; e++) {
                f16 hh = (f16)xs[e];
                h[e] = hh;
                l[e] = (f16)(xs[e] - (float)hh);
            }
            *(f16x8*)&Shi[r * PAD_PITCH + cc * 8] = h;
            *(f16x8*)&Slo[r * PAD_PITCH + cc * 8] = l;
        }
    }
}

// C = A * B^T. A: [M,K], B: [Nc,K] row-major (per batch plane).
// Tile 128x128, BK=32, 256 threads = 4 waves, each wave 64x64 (4x4 of 16x16x32).
template<StageMode SA, StageMode SB, EpiMode EP, int GROUPM, bool STATS>
__global__ __launch_bounds__(256, 4)
void mfma_gemm(const void* __restrict__ Ahi, const void* __restrict__ Alo,
               const void* __restrict__ Bhi, const void* __restrict__ Blo,
               const float* __restrict__ statM, const float* __restrict__ statR,
               float* __restrict__ pmOut, float* __restrict__ psOut,
               void* __restrict__ C0, void* __restrict__ C1,
               int M, int Nc, int K, int lda, int ldb, int ldc,
               long batchA, long batchB, long batchC,
               float epiScale, int tsShift)
{
    constexpr bool TRIPLE = (SA == SM_F32SPLIT || SA == SM_PLANES2);
    constexpr bool A_GLL  = (SA == SM_PLANES2 || SA == SM_PLANES1);
    constexpr bool B_GLL  = (SB == SM_PLANES2 || SB == SM_PLANES1);
    constexpr int A_SZ = A_GLL ? 128 * GLL_PITCH : 128 * PAD_PITCH;
    constexpr int B_SZ = B_GLL ? 128 * GLL_PITCH : 128 * PAD_PITCH;

    int bx, by;
    if constexpr (GROUPM > 0) {
        int gx = gridDim.x;
        int lin = blockIdx.y * gx + blockIdx.x;
        int nig = GROUPM * gx;
        int gid = lin / nig;
        int rem = lin - gid * nig;
        by = gid * GROUPM + (rem % GROUPM);
        bx = rem / GROUPM;
    } else {
        bx = blockIdx.x;
        by = blockIdx.y;
    }
    const int n0 = bx * 128;
    const int m0 = by * 128;
    const long z = blockIdx.z;

    long aOfs = z * batchA, bOfs = z * batchB, cOfs = z * batchC;
    const float* pM = statM + z * (long)K;   // SM_EXP only
    const float* pR = statR + z * (long)K;

    __shared__ __align__(16) f16 As_hi[A_SZ];
    __shared__ __align__(16) f16 Bs_hi[B_SZ];
    __shared__ __align__(16) f16 As_lo[TRIPLE ? A_SZ : 8];
    __shared__ __align__(16) f16 Bs_lo[TRIPLE ? B_SZ : 8];

    const int tid  = threadIdx.x;
    const int lane = tid & 63;
    const int wave = tid >> 6;
    const int wr = (wave >> 1) * 64;
    const int wc = (wave & 1) * 64;
    const int fm = lane & 15;
    const int fg = lane >> 4;        // k-chunk index 0..3
    const int fk = fg * 8;

    f32x4 acc[4][4];
#pragma unroll
    for (int i = 0; i < 4; i++)
#pragma unroll
        for (int j = 0; j < 4; j++) acc[i][j] = (f32x4){0.f, 0.f, 0.f, 0.f};

    // precompute fragment LDS offsets (layout differs per operand)
    int roA[4], roB[4];
#pragma unroll
    for (int i = 0; i < 4; i++) {
        int rowA = wr + i * 16 + fm;
        int rowB = wc + i * 16 + fm;
        roA[i] = A_GLL ? frag_off_gll(rowA, fg) : frag_off_pad(rowA, fg);
        roB[i] = B_GLL ? frag_off_gll(rowB, fg) : frag_off_pad(rowB, fg);
    }

    for (int k0 = 0; k0 < K; k0 += 32) {
        // ---- stage A ----
        if constexpr (SA == SM_PLANES2) {
            stage_gll_plane((const f16*)Ahi + aOfs, As_hi, m0, lda, k0, wave, lane);
            stage_gll_plane((const f16*)Alo + aOfs, As_lo, m0, lda, k0, wave, lane);
        } else if constexpr (SA == SM_PLANES1) {
            stage_gll_plane((const f16*)Ahi + aOfs, As_hi, m0, lda, k0, wave, lane);
        } else {
            stage_f32_tile<SA>((const float*)Ahi + aOfs, pM, pR, As_hi, As_lo, m0, lda, k0, tid);
        }
        // ---- stage B ----
        if constexpr (SB == SM_PLANES2) {
            stage_gll_plane((const f16*)Bhi + bOfs, Bs_hi, n0, ldb, k0, wave, lane);
            stage_gll_plane((const f16*)Blo + bOfs, Bs_lo, n0, ldb, k0, wave, lane);
        } else if constexpr (SB == SM_PLANES1) {
            stage_gll_plane((const f16*)Bhi + bOfs, Bs_hi, n0, ldb, k0, wave, lane);
        } else {
            stage_f32_tile<SB>((const float*)Bhi + bOfs, nullptr, nullptr, Bs_hi, Bs_lo, n0, ldb, k0, tid);
        }
        __syncthreads();

        f16x8 ah[4], bh[4], al[4], bl[4];
#pragma unroll
        for (int i = 0; i < 4; i++) {
            ah[i] = *(const f16x8*)&As_hi[roA[i]];
            bh[i] = *(const f16x8*)&Bs_hi[roB[i]];
            if constexpr (TRIPLE) {
                al[i] = *(const f16x8*)&As_lo[roA[i]];
                bl[i] = *(const f16x8*)&Bs_lo[roB[i]];
            }
        }
#pragma unroll
        for (int i = 0; i < 4; i++) {
#pragma unroll
            for (int j = 0; j < 4; j++) {
                acc[i][j] = __builtin_amdgcn_mfma_f32_16x16x32_f16(ah[i], bh[j], acc[i][j], 0, 0, 0);
                if constexpr (TRIPLE) {
                    acc[i][j] = __builtin_amdgcn_mfma_f32_16x16x32_f16(ah[i], bl[j], acc[i][j], 0, 0, 0);
                    acc[i][j] = __builtin_amdgcn_mfma_f32_16x16x32_f16(al[i], bh[j], acc[i][j], 0, 0, 0);
                }
            }
        }
        __syncthreads();
    }

    // Epilogue. C/D frag: col = lane&15, row = (lane>>4)*4 + reg  [m89-verified]
    const int cr = fg * 4;
    const int cn = fm;
#pragma unroll
    for (int i = 0; i < 4; i++) {
#pragma unroll
        for (int j = 0; j < 4; j++) {
#pragma unroll
            for (int r = 0; r < 4; r++) {
                long mg = m0 + wr + i * 16 + cr + r;
                long ng = n0 + wc + j * 16 + cn;
                float val = acc[i][j][r] * epiScale;
                if constexpr (EP == EPI_F32) {
                    ((float*)C0)[cOfs + mg * ldc + ng] = val;
                } else if constexpr (EP == EPI_SPLIT) {
                    f16 h = (f16)val;
                    ((f16*)C0)[cOfs + mg * ldc + ng] = h;
                    ((f16*)C1)[cOfs + mg * ldc + ng] = (f16)(val - (float)h);
                } else { // EPI_F16T: batch folded in M; write [nb][n][s], hi only
                    long TS = 1L << tsShift;
                    long nb = mg >> tsShift;
                    long s  = mg & (TS - 1);
                    long addr = nb * ((long)Nc << tsShift) + ng * TS + s;
                    ((f16*)C0)[addr] = (f16)val;
                }
            }
        }
    }

    // Fused column-softmax partials: per-column (max, expsum) over this tile's
    // 128 rows (q). Requires epiScale == 1 (stats on raw acc == stored Sc).
    if constexpr (STATS) {
        __shared__ float stM[2][128];
        __shared__ float stS[2][128];
#pragma unroll
        for (int j = 0; j < 4; j++) {
            float mj = -3.402823466e38f;
#pragma unroll
            for (int i = 0; i < 4; i++)
#pragma unroll
                for (int r = 0; r < 4; r++) mj = fmaxf(mj, acc[i][j][r]);
            float sj = 0.f;
#pragma unroll
            for (int i = 0; i < 4; i++)
#pragma unroll
                for (int r = 0; r < 4; r++) sj += __expf(acc[i][j][r] - mj);
            // combine the 4 lane-groups (same column, different row quads)
#pragma unroll
            for (int mask = 16; mask <= 32; mask <<= 1) {
                float mo = __shfl_xor(mj, mask, 64);
                float so = __shfl_xor(sj, mask, 64);
                float mn = fmaxf(mj, mo);
                sj = sj * __expf(mj - mn) + so * __expf(mo - mn);
                mj = mn;
            }
            if (fg == 0) {
                stM[wave >> 1][wc + j * 16 + cn] = mj;
                stS[wave >> 1][wc + j * 16 + cn] = sj;
            }
        }
        __syncthreads();
        if (tid < 128) {
            float ma = stM[0][tid], mb = stM[1][tid];
            float Mc = fmaxf(ma, mb);
            float Sv = stS[0][tid] * __expf(ma - Mc) + stS[1][tid] * __expf(mb - Mc);
            long o = ((long)z * (M >> 7) + by) * (long)Nc + (long)bx * 128 + tid;
            pmOut[o] = Mc;
            psOut[o] = Sv;
        }
    }
}

// Fold the 16 q-chunk partials -> m[k], r[k] = 1/sum.
__global__ __launch_bounds__(64)
void stats_combine_kernel(const float* __restrict__ pm, const float* __restrict__ ps,
                          float* __restrict__ statM, float* __restrict__ statR, int S)
{
    const int n = blockIdx.y;
    const int kk = blockIdx.x * 64 + threadIdx.x;
    float M = -INFINITY;
#pragma unroll
    for (int i = 0; i < 16; i++)
        M = fmaxf(M, pm[((long)n * 16 + i) * S + kk]);
    float Ssum = 0.f;
#pragma unroll
    for (int i = 0; i < 16; i++)
        Ssum += ps[((long)n * 16 + i) * S + kk] * __expf(pm[((long)n * 16 + i) * S + kk] - M);
    statM[(long)n * S + kk] = M;
    statR[(long)n * S + kk] = 1.0f / Ssum;
}

extern "C" void kernel_launch(void* const* d_in, const int* in_sizes, int n_in,
                              void* d_out, int out_size, void* d_ws, size_t ws_size,
                              hipStream_t stream)
{
    const float* v  = (const float*)d_in[0];
    const float* k  = (const float*)d_in[1];
    const float* q  = (const float*)d_in[2];
    const float* WV = (const float*)d_in[3];
    const float* WQ = (const float*)d_in[4];
    const float* WK = (const float*)d_in[5];
    float* out = (float*)d_out;

    const int N = 4, S = 2048, D = 1024;
    const long NSD = (long)N * S * D;   // 8.39M
    const long NSS = (long)N * S * S;   // 16.78M

    f16* ws = (f16*)d_ws;
    f16* wq_hi = ws;
    f16* wq_lo = ws + NSD;
    f16* wk_hi = ws + 2 * NSD;
    f16* wk_lo = ws + 3 * NSD;
    f16* wvT_hi = ws + 4 * NSD;              // [N][D][S]
    float* Sc   = (float*)(ws + 5 * NSD);    // NSS floats = 4*NSD f16 units
    float* pm    = (float*)(ws + 9 * NSD);   // [N][16][S]
    float* ps    = pm + (long)N * 16 * S;    // [N][16][S]
    float* statM = ps + (long)N * 16 * S;    // [N][S]
    float* statR = statM + (long)N * S;      // [N][S]

    dim3 blk(256);

    // Projections: M = N*S folded, C = X @ W^T
    {
        dim3 g(D / 128, (N * S) / 128, 1);
        mfma_gemm<SM_F32SPLIT, SM_F32SPLIT, EPI_SPLIT, 4, false><<<g, blk, 0, stream>>>(
            q, nullptr, WQ, nullptr, nullptr, nullptr, nullptr, nullptr, wq_hi, wq_lo,
            N * S, D, D, D, D, D, 0, 0, 0, 1.0f, 0);
        mfma_gemm<SM_F32SPLIT, SM_F32SPLIT, EPI_SPLIT, 4, false><<<g, blk, 0, stream>>>(
            k, nullptr, WK, nullptr, nullptr, nullptr, nullptr, nullptr, wk_hi, wk_lo,
            N * S, D, D, D, D, D, 0, 0, 0, 1.0f, 0);
        mfma_gemm<SM_F32HI, SM_F32HI, EPI_F16T, 4, false><<<g, blk, 0, stream>>>(
            v, nullptr, WV, nullptr, nullptr, nullptr, nullptr, nullptr, wvT_hi, nullptr,
            N * S, D, D, D, D, 0, 0, 0, 0, 1.0f, 11 /* tsShift: S=2048 */);
    }
    // Scores: Sc[n] = wq[n] @ wk[n]^T (f32 out) + fused column-stat partials
    {
        dim3 g(S / 128, S / 128, N);
        mfma_gemm<SM_PLANES2, SM_PLANES2, EPI_F32, 4, true><<<g, blk, 0, stream>>>(
            wq_hi, wq_lo, wk_hi, wk_lo, nullptr, nullptr, pm, ps, Sc, nullptr,
            S, S, D, D, D, S, (long)S * D, (long)S * D, (long)S * S, 1.0f, 0);
    }
    // Combine partials -> statM, statR
    {
        dim3 gB(S / 64, N);
        stats_combine_kernel<<<gB, dim3(64), 0, stream>>>(pm, ps, statM, statR, S);
    }
    // out[n] = (P[n] @ wvT[n]^T) / 1024 ; P computed in A-staging from Sc + stats
    {
        dim3 g(D / 128, S / 128, N);
        mfma_gemm<SM_EXP, SM_PLANES1, EPI_F32, 0, false><<<g, blk, 0, stream>>>(
            Sc, nullptr, wvT_hi, nullptr, statM, statR, nullptr, nullptr, out, nullptr,
            S, D, S, S, S, D, (long)S * S, (long)S * D, (long)S * D, 1.0f / (float)D, 0);
    }
}

// Round 6
// 471.828 us; speedup vs baseline: 1.1258x; 1.1258x over previous
//
#include <hip/hip_runtime.h>
#include <math.h>

// N=4, S=2048, D=1024, fp32 in/out.
// Pipeline (ALL GEMMs are GLL-staged f16-plane MFMA; conversion happens once in a pre-pass):
//   split   : q,k -> hi/lo planes ; v,WV -> hi ; WQ,WK -> hi/lo
//   wq = q@WQt, wk = k@WKt : triple-product (hh+hl+lh) GLL GEMM, split-plane out
//   wvT = (v@WVt)^T        : single-product GLL GEMM, f16 hi transposed out [n][o][s]
//   Sc = wq@wkt            : triple GLL GEMM, f32 out + fused column-stat partials
//   combine                : fold 16 q-chunk partials -> m[k], r[k]=1/sum
//   pmat                   : P_hi = (f16) exp(Sc - m[k]) * r[k]
//   out = (P @ wvT^T)/1024 : single-product GLL GEMM, f32 out
// Workspace (f16 units, NSD = 8388608, DD = 1048576; peak 9.625*NSD < 10*NSD budget):
//   [0,1)N      q_hi   ; later wvT_hi (q dead after q-proj)
//   [1,2)N      q_lo   ; later Sc f32 spans [1,5)N (q_lo/k/v dead by then)
//   [2,4)N      k_hi|k_lo
//   [4,5)N      v_hi
//   [5N,5N+5DD) WQ_hi|WQ_lo|WK_hi|WK_lo|WV_hi
//   [5N+5DD, 9N+5DD) wq_hi|wq_lo|wk_hi|wk_lo ; later P_hi aliases wq_hi..(2N)
//   [9N+5DD, ..) stats (pm|ps|statM|statR, ~1.1 MB)

typedef _Float16 f16;
typedef _Float16 f16x8 __attribute__((ext_vector_type(8)));
typedef _Float16 f16x4 __attribute__((ext_vector_type(4)));
typedef float f32x4 __attribute__((ext_vector_type(4)));

enum StageMode { SM_PLANES2, SM_PLANES1 };
enum EpiMode   { EPI_F32, EPI_SPLIT, EPI_F16T };

#define GLL_PITCH 32   // f16 units/row; unpadded, XOR-swizzled 16B chunks

// async global->LDS, 16B per lane; LDS dest = wave-uniform base + lane*16
__device__ __forceinline__ void gll16(const f16* g, f16* l) {
    __builtin_amdgcn_global_load_lds(
        (const __attribute__((address_space(1))) void*)g,
        (__attribute__((address_space(3))) void*)l, 16, 0, 0);
}

// Stage one 128x32 f16 plane via GLL with XOR chunk swizzle.
// Physical 16B slot t holds data (row = t>>2, chunk = (t&3) ^ ((row>>1)&3)).
__device__ __forceinline__ void stage_gll_plane(const f16* __restrict__ gplane,
                                                f16* __restrict__ lds,
                                                long rowBase, int ld, int k0,
                                                int wave, int lane)
{
#pragma unroll
    for (int i = 0; i < 2; i++) {
        int slotBase = (wave * 2 + i) * 64;
        int t = slotBase + lane;
        int r = t >> 2;
        int c = (t & 3) ^ ((r >> 1) & 3);
        const f16* g = gplane + (rowBase + r) * (long)ld + k0 + c * 8;
        gll16(g, lds + (long)slotBase * 8);   // wave-uniform LDS base
    }
}

__device__ __forceinline__ int frag_off_gll(int row, int g) {
    return row * GLL_PITCH + ((g ^ ((row >> 1) & 3)) << 3);
}

// C = A * B^T. A: [M,K], B: [Nc,K] row-major f16 planes (per batch plane).
// Tile 128x128, BK=32, 256 threads = 4 waves, each wave 64x64 (4x4 of 16x16x32).
template<StageMode SA, StageMode SB, EpiMode EP, int GROUPM, bool STATS>
__global__ __launch_bounds__(256, 4)
void mfma_gemm(const f16* __restrict__ Ahi, const f16* __restrict__ Alo,
               const f16* __restrict__ Bhi, const f16* __restrict__ Blo,
               float* __restrict__ pmOut, float* __restrict__ psOut,
               void* __restrict__ C0, void* __restrict__ C1,
               int M, int Nc, int K, int lda, int ldb, int ldc,
               long batchA, long batchB, long batchC,
               float epiScale, int tsShift)
{
    constexpr bool TRIPLE = (SA == SM_PLANES2);
    constexpr int PLANE_SZ = 128 * GLL_PITCH;

    int bx, by;
    if constexpr (GROUPM > 0) {
        int gx = gridDim.x;
        int lin = blockIdx.y * gx + blockIdx.x;
        int nig = GROUPM * gx;
        int gid = lin / nig;
        int rem = lin - gid * nig;
        by = gid * GROUPM + (rem % GROUPM);
        bx = rem / GROUPM;
    } else {
        bx = blockIdx.x;
        by = blockIdx.y;
    }
    const int n0 = bx * 128;
    const int m0 = by * 128;
    const long z = blockIdx.z;

    const long aOfs = z * batchA, bOfs = z * batchB, cOfs = z * batchC;

    __shared__ __align__(16) f16 As_hi[PLANE_SZ];
    __shared__ __align__(16) f16 Bs_hi[PLANE_SZ];
    __shared__ __align__(16) f16 As_lo[TRIPLE ? PLANE_SZ : 8];
    __shared__ __align__(16) f16 Bs_lo[TRIPLE ? PLANE_SZ : 8];

    const int tid  = threadIdx.x;
    const int lane = tid & 63;
    const int wave = tid >> 6;
    const int wr = (wave >> 1) * 64;
    const int wc = (wave & 1) * 64;
    const int fm = lane & 15;
    const int fg = lane >> 4;        // k-chunk index 0..3

    f32x4 acc[4][4];
#pragma unroll
    for (int i = 0; i < 4; i++)
#pragma unroll
        for (int j = 0; j < 4; j++) acc[i][j] = (f32x4){0.f, 0.f, 0.f, 0.f};

    int roA[4], roB[4];
#pragma unroll
    for (int i = 0; i < 4; i++) {
        roA[i] = frag_off_gll(wr + i * 16 + fm, fg);
        roB[i] = frag_off_gll(wc + i * 16 + fm, fg);
    }

    for (int k0 = 0; k0 < K; k0 += 32) {
        stage_gll_plane(Ahi + aOfs, As_hi, m0, lda, k0, wave, lane);
        stage_gll_plane(Bhi + bOfs, Bs_hi, n0, ldb, k0, wave, lane);
        if constexpr (TRIPLE) {
            stage_gll_plane(Alo + aOfs, As_lo, m0, lda, k0, wave, lane);
            stage_gll_plane(Blo + bOfs, Bs_lo, n0, ldb, k0, wave, lane);
        }
        __syncthreads();

        f16x8 ah[4], bh[4], al[4], bl[4];
#pragma unroll
        for (int i = 0; i < 4; i++) {
            ah[i] = *(const f16x8*)&As_hi[roA[i]];
            bh[i] = *(const f16x8*)&Bs_hi[roB[i]];
            if constexpr (TRIPLE) {
                al[i] = *(const f16x8*)&As_lo[roA[i]];
                bl[i] = *(const f16x8*)&Bs_lo[roB[i]];
            }
        }
#pragma unroll
        for (int i = 0; i < 4; i++) {
#pragma unroll
            for (int j = 0; j < 4; j++) {
                acc[i][j] = __builtin_amdgcn_mfma_f32_16x16x32_f16(ah[i], bh[j], acc[i][j], 0, 0, 0);
                if constexpr (TRIPLE) {
                    acc[i][j] = __builtin_amdgcn_mfma_f32_16x16x32_f16(ah[i], bl[j], acc[i][j], 0, 0, 0);
                    acc[i][j] = __builtin_amdgcn_mfma_f32_16x16x32_f16(al[i], bh[j], acc[i][j], 0, 0, 0);
                }
            }
        }
        __syncthreads();
    }

    // Epilogue. C/D frag: col = lane&15, row = (lane>>4)*4 + reg  [m89-verified]
    const int cr = fg * 4;
    const int cn = fm;
#pragma unroll
    for (int i = 0; i < 4; i++) {
#pragma unroll
        for (int j = 0; j < 4; j++) {
#pragma unroll
            for (int r = 0; r < 4; r++) {
                long mg = m0 + wr + i * 16 + cr + r;
                long ng = n0 + wc + j * 16 + cn;
                float val = acc[i][j][r] * epiScale;
                if constexpr (EP == EPI_F32) {
                    ((float*)C0)[cOfs + mg * ldc + ng] = val;
                } else if constexpr (EP == EPI_SPLIT) {
                    f16 h = (f16)val;
                    ((f16*)C0)[cOfs + mg * ldc + ng] = h;
                    ((f16*)C1)[cOfs + mg * ldc + ng] = (f16)(val - (float)h);
                } else { // EPI_F16T: batch folded in M; write [nb][n][s], hi only
                    long TS = 1L << tsShift;
                    long nb = mg >> tsShift;
                    long s  = mg & (TS - 1);
                    long addr = nb * ((long)Nc << tsShift) + ng * TS + s;
                    ((f16*)C0)[addr] = (f16)val;
                }
            }
        }
    }

    // Fused column-softmax partials over this tile's 128 rows (q). epiScale==1 required.
    if constexpr (STATS) {
        __shared__ float stM[2][128];
        __shared__ float stS[2][128];
#pragma unroll
        for (int j = 0; j < 4; j++) {
            float mj = -3.402823466e38f;
#pragma unroll
            for (int i = 0; i < 4; i++)
#pragma unroll
                for (int r = 0; r < 4; r++) mj = fmaxf(mj, acc[i][j][r]);
            float sj = 0.f;
#pragma unroll
            for (int i = 0; i < 4; i++)
#pragma unroll
                for (int r = 0; r < 4; r++) sj += __expf(acc[i][j][r] - mj);
#pragma unroll
            for (int mask = 16; mask <= 32; mask <<= 1) {
                float mo = __shfl_xor(mj, mask, 64);
                float so = __shfl_xor(sj, mask, 64);
                float mn = fmaxf(mj, mo);
                sj = sj * __expf(mj - mn) + so * __expf(mo - mn);
                mj = mn;
            }
            if (fg == 0) {
                stM[wave >> 1][wc + j * 16 + cn] = mj;
                stS[wave >> 1][wc + j * 16 + cn] = sj;
            }
        }
        __syncthreads();
        if (tid < 128) {
            float ma = stM[0][tid], mb = stM[1][tid];
            float Mc = fmaxf(ma, mb);
            float Sv = stS[0][tid] * __expf(ma - Mc) + stS[1][tid] * __expf(mb - Mc);
            long o = ((long)z * (M >> 7) + by) * (long)Nc + (long)bx * 128 + tid;
            pmOut[o] = Mc;
            psOut[o] = Sv;
        }
    }
}

// Elementwise f32 -> f16 hi (+ optional lo) split. n multiple of 2048.
template<bool HAS_LO>
__global__ __launch_bounds__(256)
void split_kernel(const float* __restrict__ src, f16* __restrict__ hi,
                  f16* __restrict__ lo, long n)
{
    long i = ((long)blockIdx.x * 256 + threadIdx.x) * 8;
    if (i >= n) return;
    float4 x0 = *(const float4*)&src[i];
    float4 x1 = *(const float4*)&src[i + 4];
    float xs[8] = {x0.x, x0.y, x0.z, x0.w, x1.x, x1.y, x1.z, x1.w};
    f16x8 h, l;
#pragma unroll
    for (int e = 0; e < 8; e++) {
        f16 hh = (f16)xs[e];
        h[e] = hh;
        if (HAS_LO) l[e] = (f16)(xs[e] - (float)hh);
    }
    *(f16x8*)&hi[i] = h;
    if (HAS_LO) *(f16x8*)&lo[i] = l;
}

// Fold the 16 q-chunk partials -> m[k], r[k] = 1/sum.
__global__ __launch_bounds__(64)
void stats_combine_kernel(const float* __restrict__ pm, const float* __restrict__ ps,
                          float* __restrict__ statM, float* __restrict__ statR, int S)
{
    const int n = blockIdx.y;
    const int kk = blockIdx.x * 64 + threadIdx.x;
    float M = -INFINITY;
#pragma unroll
    for (int i = 0; i < 16; i++)
        M = fmaxf(M, pm[((long)n * 16 + i) * S + kk]);
    float Ssum = 0.f;
#pragma unroll
    for (int i = 0; i < 16; i++)
        Ssum += ps[((long)n * 16 + i) * S + kk] * __expf(pm[((long)n * 16 + i) * S + kk] - M);
    statM[(long)n * S + kk] = M;
    statR[(long)n * S + kk] = 1.0f / Ssum;
}

// P_hi = (f16)(exp(Sc - m[k]) * r[k]).  Grid: (S/1024, S/32, N); thread = 4 k cols.
__global__ __launch_bounds__(256)
void pmat_kernel(const float* __restrict__ Sc, const float* __restrict__ statM,
                 const float* __restrict__ statR, f16* __restrict__ Phi, int S)
{
    const int n = blockIdx.z;
    const int kk = blockIdx.x * 1024 + threadIdx.x * 4;
    const float* Sn = Sc + (long)n * S * S;
    f16* ph = Phi + (long)n * S * S;
    float4 M4 = *(const float4*)&statM[(long)n * S + kk];
    float4 R4 = *(const float4*)&statR[(long)n * S + kk];
    const int q0 = blockIdx.y * 32;
    for (int qi = 0; qi < 32; qi++) {
        long idx = (long)(q0 + qi) * S + kk;
        float4 x = *(const float4*)&Sn[idx];
        f16x4 p;
        p[0] = (f16)(__expf(x.x - M4.x) * R4.x);
        p[1] = (f16)(__expf(x.y - M4.y) * R4.y);
        p[2] = (f16)(__expf(x.z - M4.z) * R4.z);
        p[3] = (f16)(__expf(x.w - M4.w) * R4.w);
        *(f16x4*)&ph[idx] = p;
    }
}

extern "C" void kernel_launch(void* const* d_in, const int* in_sizes, int n_in,
                              void* d_out, int out_size, void* d_ws, size_t ws_size,
                              hipStream_t stream)
{
    const float* v  = (const float*)d_in[0];
    const float* k  = (const float*)d_in[1];
    const float* q  = (const float*)d_in[2];
    const float* WV = (const float*)d_in[3];
    const float* WQ = (const float*)d_in[4];
    const float* WK = (const float*)d_in[5];
    float* out = (float*)d_out;

    const int N = 4, S = 2048, D = 1024;
    const long NSD = (long)N * S * D;   // 8388608
    const long DD  = (long)D * D;       // 1048576

    f16* ws = (f16*)d_ws;
    // phase-1 buffers
    f16* q_hi = ws;                 // [0,1)N
    f16* q_lo = ws + NSD;           // [1,2)N
    f16* k_hi = ws + 2 * NSD;
    f16* k_lo = ws + 3 * NSD;
    f16* v_hi = ws + 4 * NSD;
    f16* Wb   = ws + 5 * NSD;       // weight planes
    f16* WQ_hi = Wb,          *WQ_lo = Wb + DD;
    f16* WK_hi = Wb + 2 * DD, *WK_lo = Wb + 3 * DD;
    f16* WV_hi = Wb + 4 * DD;
    // projection outputs
    f16* wq_hi = ws + 5 * NSD + 5 * DD;
    f16* wq_lo = wq_hi + NSD;
    f16* wk_hi = wq_hi + 2 * NSD;
    f16* wk_lo = wq_hi + 3 * NSD;
    // aliases (lifetime-checked):
    f16* wvT_hi = ws;                       // [0,1)N — q_hi dead after q-proj
    float* Sc   = (float*)(ws + NSD);       // [1,5)N — q_lo/k/v dead by scores
    f16* P_hi   = wq_hi;                    // wq/wk dead after scores
    // stats
    float* pm    = (float*)(ws + 9 * NSD + 5 * DD);   // [N][16][S]
    float* ps    = pm + (long)N * 16 * S;
    float* statM = ps + (long)N * 16 * S;
    float* statR = statM + (long)N * S;

    dim3 blk(256);

    // ---- split pre-pass ----
    split_kernel<true ><<<dim3(NSD / 2048), blk, 0, stream>>>(q,  q_hi, q_lo, NSD);
    split_kernel<true ><<<dim3(NSD / 2048), blk, 0, stream>>>(k,  k_hi, k_lo, NSD);
    split_kernel<false><<<dim3(NSD / 2048), blk, 0, stream>>>(v,  v_hi, nullptr, NSD);
    split_kernel<true ><<<dim3(DD / 2048),  blk, 0, stream>>>(WQ, WQ_hi, WQ_lo, DD);
    split_kernel<true ><<<dim3(DD / 2048),  blk, 0, stream>>>(WK, WK_hi, WK_lo, DD);
    split_kernel<false><<<dim3(DD / 2048),  blk, 0, stream>>>(WV, WV_hi, nullptr, DD);

    // ---- projections: M = N*S folded, C = X @ W^T ----
    {
        dim3 g(D / 128, (N * S) / 128, 1);
        mfma_gemm<SM_PLANES2, SM_PLANES2, EPI_SPLIT, 4, false><<<g, blk, 0, stream>>>(
            q_hi, q_lo, WQ_hi, WQ_lo, nullptr, nullptr, wq_hi, wq_lo,
            N * S, D, D, D, D, D, 0, 0, 0, 1.0f, 0);
        mfma_gemm<SM_PLANES2, SM_PLANES2, EPI_SPLIT, 4, false><<<g, blk, 0, stream>>>(
            k_hi, k_lo, WK_hi, WK_lo, nullptr, nullptr, wk_hi, wk_lo,
            N * S, D, D, D, D, D, 0, 0, 0, 1.0f, 0);
        mfma_gemm<SM_PLANES1, SM_PLANES1, EPI_F16T, 4, false><<<g, blk, 0, stream>>>(
            v_hi, nullptr, WV_hi, nullptr, nullptr, nullptr, wvT_hi, nullptr,
            N * S, D, D, D, D, 0, 0, 0, 0, 1.0f, 11 /* tsShift: S=2048 */);
    }
    // ---- scores: Sc[n] = wq[n] @ wk[n]^T (f32) + fused column-stat partials ----
    {
        dim3 g(S / 128, S / 128, N);
        mfma_gemm<SM_PLANES2, SM_PLANES2, EPI_F32, 4, true><<<g, blk, 0, stream>>>(
            wq_hi, wq_lo, wk_hi, wk_lo, pm, ps, Sc, nullptr,
            S, S, D, D, D, S, (long)S * D, (long)S * D, (long)S * S, 1.0f, 0);
    }
    // ---- combine partials -> statM, statR ----
    {
        dim3 gB(S / 64, N);
        stats_combine_kernel<<<gB, dim3(64), 0, stream>>>(pm, ps, statM, statR, S);
    }
    // ---- P_hi = exp(Sc - m)*r ----
    {
        dim3 g(S / 1024, S / 32, N);
        pmat_kernel<<<g, blk, 0, stream>>>(Sc, statM, statR, P_hi, S);
    }
    // ---- out[n] = (P[n] @ wvT[n]^T) / 1024 ----
    {
        dim3 g(D / 128, S / 128, N);
        mfma_gemm<SM_PLANES1, SM_PLANES1, EPI_F32, 4, false><<<g, blk, 0, stream>>>(
            P_hi, nullptr, wvT_hi, nullptr, nullptr, nullptr, out, nullptr,
            S, D, S, S, S, D, (long)S * S, (long)S * D, (long)S * D, 1.0f / (float)D, 0);
    }
}